// Round 1
// baseline (8675.973 us; speedup 1.0000x reference)
//
#include <hip/hip_runtime.h>

#define NN   50000
#define DD   128
#define RR   3
#define EE   800000
#define OUTD 64
#define ALPHA_ 0.5f
#define SLOPE_ 0.01f
#define BETA1_ 0.6931471805599453f   // log(2)
#define BETA2_ 0.4054651081081644f   // log(1.5)

// ---------------- degree kernels ----------------
__global__ __launch_bounds__(256) void deg_count_kernel(
    const int* __restrict__ src, const int* __restrict__ dst,
    float* __restrict__ dego, float* __restrict__ degi)
{
    const int tid = blockIdx.x * 256 + threadIdx.x;
    if (tid >= RR * EE) return;
    const int r = tid / EE;
    const int base = r * NN;
    atomicAdd(&dego[base + src[tid]], 1.0f);
    atomicAdd(&degi[base + dst[tid]], 1.0f);
}

__global__ __launch_bounds__(256) void deg_fin_kernel(float* __restrict__ deg)
{
    const int i = blockIdx.x * 256 + threadIdx.x;
    if (i >= 2 * RR * NN) return;
    float d = deg[i];
    d = fmaxf(d, 1.0f);
    deg[i] = rsqrtf(d);
}

// ---------------- scatter-aggregate (SpMM via atomics) ----------------
// 32 lanes per edge; each lane handles one float4 (128B/32lanes*16B = full 512B row)
__global__ __launch_bounds__(256) void scatter_kernel(
    const float* __restrict__ h, const int* __restrict__ src,
    const int* __restrict__ dst, const float* __restrict__ dn_out,
    float* __restrict__ agg)
{
    const int tid = blockIdx.x * 256 + threadIdx.x;
    const int e = tid >> 5;
    if (e >= EE) return;
    const int lane = tid & 31;
    const int s = src[e];
    const int d = dst[e];
    const float ns = dn_out[s];
    const float4 v = ((const float4*)(h + (size_t)s * DD))[lane];
    float* a = agg + (size_t)d * DD + lane * 4;
    atomicAdd(a + 0, v.x * ns);
    atomicAdd(a + 1, v.y * ns);
    atomicAdd(a + 2, v.z * ns);
    atomicAdd(a + 3, v.w * ns);
}

// ---------------- post: in-place dst-normalize + initial-residual blend ----------------
__global__ __launch_bounds__(256) void post_kernel(
    float* __restrict__ agg, const float* __restrict__ dn_in,
    const float* __restrict__ x)
{
    const int i = blockIdx.x * 256 + threadIdx.x;   // float4 index
    if (i >= NN * DD / 4) return;
    const int row = i >> 5;                          // 32 float4 per row
    const float nd = dn_in[row] * (1.0f - ALPHA_);
    float4 a = ((float4*)agg)[i];
    const float4 f = ((const float4*)x)[i];
    a.x = a.x * nd + ALPHA_ * f.x;
    a.y = a.y * nd + ALPHA_ * f.y;
    a.z = a.z * nd + ALPHA_ * f.z;
    a.w = a.w * nd + ALPHA_ * f.w;
    ((float4*)agg)[i] = a;
}

// ---------------- GEMM [N,128]@[128,128] + identity-map epilogue + mean-accum ----------------
// Whole W in LDS (64KB). 64 rows/block, 16-row staged tiles; thread = (ty 0..7 -> 2 rows, lane 0..31 -> 4 cols)
__global__ __launch_bounds__(256) void gemm_ep_kernel(
    const float* __restrict__ rst, const float* __restrict__ W,
    const float* __restrict__ b, float* __restrict__ hout,
    float beta, int act)
{
    __shared__ float Wl[DD * DD];       // 64 KB
    __shared__ float rowbuf[16][DD];    // 8 KB
    __shared__ float bl[DD];
    const int tid = threadIdx.x;
    for (int i = tid; i < DD * DD / 4; i += 256)
        ((float4*)Wl)[i] = ((const float4*)W)[i];
    if (tid < DD) bl[tid] = b[tid];
    const int lane = tid & 31;
    const int ty = tid >> 5;            // 0..7
    const int r0 = ty * 2, r1 = r0 + 1;
    const float omb = 1.0f - beta;
    const int blockRow = blockIdx.x * 64;

    for (int it = 0; it < 4; ++it) {
        const int rb = blockRow + it * 16;
        __syncthreads();                 // covers W load (it=0) + rowbuf reuse
        for (int i = tid; i < 16 * DD / 4; i += 256) {
            const int rr = i >> 5, cc = i & 31;
            const int grow = rb + rr;
            float4 v = make_float4(0.f, 0.f, 0.f, 0.f);
            if (grow < NN) v = ((const float4*)(rst + (size_t)grow * DD))[cc];
            ((float4*)rowbuf)[i] = v;
        }
        __syncthreads();

        float4 a0 = make_float4(0.f, 0.f, 0.f, 0.f);
        float4 a1 = make_float4(0.f, 0.f, 0.f, 0.f);
        for (int k = 0; k < DD; ++k) {
            const float4 w = ((const float4*)(Wl + k * DD))[lane];
            const float x0 = rowbuf[r0][k];
            const float x1 = rowbuf[r1][k];
            a0.x = fmaf(x0, w.x, a0.x); a0.y = fmaf(x0, w.y, a0.y);
            a0.z = fmaf(x0, w.z, a0.z); a0.w = fmaf(x0, w.w, a0.w);
            a1.x = fmaf(x1, w.x, a1.x); a1.y = fmaf(x1, w.y, a1.y);
            a1.z = fmaf(x1, w.z, a1.z); a1.w = fmaf(x1, w.w, a1.w);
        }

        const float4 bb = ((const float4*)bl)[lane];
        #pragma unroll
        for (int p = 0; p < 2; ++p) {
            const int rr = (p == 0) ? r0 : r1;
            const float4 ac = (p == 0) ? a0 : a1;
            const int grow = rb + rr;
            if (grow < NN) {
                const float4 rv = ((const float4*)rowbuf[rr])[lane];
                float4 v;
                v.x = omb * rv.x + beta * ac.x + bb.x;
                v.y = omb * rv.y + beta * ac.y + bb.y;
                v.z = omb * rv.z + beta * ac.z + bb.z;
                v.w = omb * rv.w + beta * ac.w + bb.w;
                if (act) {
                    v.x = v.x >= 0.f ? v.x : SLOPE_ * v.x;
                    v.y = v.y >= 0.f ? v.y : SLOPE_ * v.y;
                    v.z = v.z >= 0.f ? v.z : SLOPE_ * v.z;
                    v.w = v.w >= 0.f ? v.w : SLOPE_ * v.w;
                }
                float4* ho = (float4*)(hout + (size_t)grow * DD) + lane;
                float4 o = *ho;
                o.x += v.x * (1.0f / 3.0f);
                o.y += v.y * (1.0f / 3.0f);
                o.z += v.z * (1.0f / 3.0f);
                o.w += v.w * (1.0f / 3.0f);
                *ho = o;
            }
        }
    }
}

// ---------------- final linear [N,128]@[128,64] + bias ----------------
__global__ __launch_bounds__(256) void lin_kernel(
    const float* __restrict__ h, const float* __restrict__ Wlin,
    const float* __restrict__ blin, float* __restrict__ out)
{
    __shared__ float Wl[DD * OUTD];     // 32 KB
    __shared__ float rowbuf[16][DD];    // 8 KB
    __shared__ float bl[OUTD];
    const int tid = threadIdx.x;
    for (int i = tid; i < DD * OUTD / 4; i += 256)
        ((float4*)Wl)[i] = ((const float4*)Wlin)[i];
    if (tid < OUTD) bl[tid] = blin[tid];
    const int lane = tid & 15;          // 16 lanes x 4 cols = 64 cols
    const int ty = tid >> 4;            // 0..15 rows
    const int blockRow = blockIdx.x * 64;

    for (int it = 0; it < 4; ++it) {
        const int rb = blockRow + it * 16;
        __syncthreads();
        for (int i = tid; i < 16 * DD / 4; i += 256) {
            const int rr = i >> 5, cc = i & 31;
            const int grow = rb + rr;
            float4 v = make_float4(0.f, 0.f, 0.f, 0.f);
            if (grow < NN) v = ((const float4*)(h + (size_t)grow * DD))[cc];
            ((float4*)rowbuf)[i] = v;
        }
        __syncthreads();

        float4 acc = make_float4(0.f, 0.f, 0.f, 0.f);
        for (int k = 0; k < DD; ++k) {
            const float4 w = ((const float4*)(Wl + k * OUTD))[lane];
            const float xv = rowbuf[ty][k];
            acc.x = fmaf(xv, w.x, acc.x);
            acc.y = fmaf(xv, w.y, acc.y);
            acc.z = fmaf(xv, w.z, acc.z);
            acc.w = fmaf(xv, w.w, acc.w);
        }
        const int grow = rb + ty;
        if (grow < NN) {
            const float4 bb = ((const float4*)bl)[lane];
            float4 v;
            v.x = acc.x + bb.x;
            v.y = acc.y + bb.y;
            v.z = acc.z + bb.z;
            v.w = acc.w + bb.w;
            ((float4*)(out + (size_t)grow * OUTD))[lane] = v;
        }
    }
}

extern "C" void kernel_launch(void* const* d_in, const int* in_sizes, int n_in,
                              void* d_out, int out_size, void* d_ws, size_t ws_size,
                              hipStream_t stream)
{
    const float* x    = (const float*)d_in[0];
    const int*   src  = (const int*)  d_in[1];
    const int*   dst  = (const int*)  d_in[2];
    const float* W1   = (const float*)d_in[3];
    const float* b1   = (const float*)d_in[4];
    const float* W2   = (const float*)d_in[5];
    const float* b2   = (const float*)d_in[6];
    const float* Wlin = (const float*)d_in[7];
    const float* blin = (const float*)d_in[8];
    float* out = (float*)d_out;

    // workspace layout (floats): dego[R*N] | degi[R*N] | agg[N*D] | h1[N*D] | h2[N*D]  ~78 MB
    float* ws   = (float*)d_ws;
    float* dego = ws;
    float* degi = dego + RR * NN;
    float* agg  = degi + RR * NN;
    float* h1   = agg + (size_t)NN * DD;
    float* h2   = h1  + (size_t)NN * DD;

    hipMemsetAsync(dego, 0, (size_t)2 * RR * NN * sizeof(float), stream);
    hipMemsetAsync(h1,   0, (size_t)NN * DD * sizeof(float), stream);
    hipMemsetAsync(h2,   0, (size_t)NN * DD * sizeof(float), stream);

    deg_count_kernel<<<(RR * EE + 255) / 256, 256, 0, stream>>>(src, dst, dego, degi);
    deg_fin_kernel<<<(2 * RR * NN + 255) / 256, 256, 0, stream>>>(dego);

    const int scatter_blocks = (EE * 32) / 256;        // exact
    const int post_blocks    = (NN * DD / 4 + 255) / 256;
    const int gemm_blocks    = (NN + 63) / 64;

    // ---- conv1: h1 = mean_r gcn2(x, x, W1_r, b1_r, beta1, leaky) ----
    for (int r = 0; r < RR; ++r) {
        hipMemsetAsync(agg, 0, (size_t)NN * DD * sizeof(float), stream);
        scatter_kernel<<<scatter_blocks, 256, 0, stream>>>(
            x, src + (size_t)r * EE, dst + (size_t)r * EE, dego + r * NN, agg);
        post_kernel<<<post_blocks, 256, 0, stream>>>(agg, degi + r * NN, x);
        gemm_ep_kernel<<<gemm_blocks, 256, 0, stream>>>(
            agg, W1 + (size_t)r * DD * DD, b1 + r * DD, h1, BETA1_, 1);
    }
    // ---- conv2: h2 = mean_r gcn2(h1, x, W2_r, b2_r, beta2, no act) ----
    for (int r = 0; r < RR; ++r) {
        hipMemsetAsync(agg, 0, (size_t)NN * DD * sizeof(float), stream);
        scatter_kernel<<<scatter_blocks, 256, 0, stream>>>(
            h1, src + (size_t)r * EE, dst + (size_t)r * EE, dego + r * NN, agg);
        post_kernel<<<post_blocks, 256, 0, stream>>>(agg, degi + r * NN, x);
        gemm_ep_kernel<<<gemm_blocks, 256, 0, stream>>>(
            agg, W2 + (size_t)r * DD * DD, b2 + r * DD, h2, BETA2_, 0);
    }
    // ---- final linear ----
    lin_kernel<<<gemm_blocks, 256, 0, stream>>>(h2, Wlin, blin, out);
}

// Round 2
// 1205.763 us; speedup vs baseline: 7.1954x; 7.1954x over previous
//
#include <hip/hip_runtime.h>

#define NN   50000
#define DD   128
#define RR   3
#define EE   800000
#define OUTD 64
#define NB   196                      // ceil(NN/256)
#define ALPHA_ 0.5f
#define SLOPE_ 0.01f
#define BETA1_ 0.6931471805599453f    // log(2)
#define BETA2_ 0.4054651081081644f    // log(1.5)

// ---------------- degree count (int atomics) ----------------
__global__ __launch_bounds__(256) void deg_count_kernel(
    const int* __restrict__ src, const int* __restrict__ dst,
    int* __restrict__ cnt_out, int* __restrict__ cnt_in)
{
    const int tid = blockIdx.x * 256 + threadIdx.x;
    if (tid >= RR * EE) return;
    const int r = tid / EE;
    const int base = r * NN;
    atomicAdd(&cnt_out[base + src[tid]], 1);
    atomicAdd(&cnt_in[base + dst[tid]], 1);
}

// rsqrt(max(cnt,1)) for both degree arrays
__global__ __launch_bounds__(256) void deg_fin_kernel(
    const int* __restrict__ cnt_out, const int* __restrict__ cnt_in,
    float* __restrict__ dego_r, float* __restrict__ degi_r)
{
    const int i = blockIdx.x * 256 + threadIdx.x;
    if (i >= RR * NN) return;
    dego_r[i] = rsqrtf((float)max(cnt_out[i], 1));
    degi_r[i] = rsqrtf((float)max(cnt_in[i], 1));
}

// ---------------- 3-kernel parallel prefix scan of cnt_in -> off, cur ----------------
__global__ __launch_bounds__(256) void scanA_kernel(   // per-256-chunk reduce
    const int* __restrict__ cnt_in, int* __restrict__ bsum)
{
    __shared__ int buf[256];
    const int bid = blockIdx.x;              // 0 .. RR*NB-1
    const int r = bid / NB, c = bid % NB;
    const int idx = c * 256 + threadIdx.x;
    buf[threadIdx.x] = (idx < NN) ? cnt_in[r * NN + idx] : 0;
    __syncthreads();
    for (int s = 128; s > 0; s >>= 1) {
        if (threadIdx.x < s) buf[threadIdx.x] += buf[threadIdx.x + s];
        __syncthreads();
    }
    if (threadIdx.x == 0) bsum[bid] = buf[0];
}

__global__ __launch_bounds__(256) void scanB_kernel(   // scan the block sums (1 block)
    const int* __restrict__ bsum, int* __restrict__ bexcl)
{
    __shared__ int buf[256];
    const int t = threadIdx.x;
    for (int r = 0; r < RR; ++r) {
        const int v = (t < NB) ? bsum[r * NB + t] : 0;
        buf[t] = v;
        __syncthreads();
        for (int s = 1; s < 256; s <<= 1) {
            const int add = (t >= s) ? buf[t - s] : 0;
            __syncthreads();
            buf[t] += add;
            __syncthreads();
        }
        if (t < NB) bexcl[r * NB + t] = buf[t] - v;
        __syncthreads();
    }
}

__global__ __launch_bounds__(256) void scanC_kernel(   // local excl scan + block offset
    const int* __restrict__ cnt_in, const int* __restrict__ bexcl,
    int* __restrict__ off, int* __restrict__ cur)
{
    __shared__ int buf[256];
    const int bid = blockIdx.x;
    const int r = bid / NB, c = bid % NB;
    const int t = threadIdx.x;
    const int idx = c * 256 + t;
    const int v = (idx < NN) ? cnt_in[r * NN + idx] : 0;
    buf[t] = v;
    __syncthreads();
    for (int s = 1; s < 256; s <<= 1) {
        const int add = (t >= s) ? buf[t - s] : 0;
        __syncthreads();
        buf[t] += add;
        __syncthreads();
    }
    if (idx < NN) {
        const int o = bexcl[bid] + buf[t] - v;
        off[r * NN + idx] = o;
        cur[r * NN + idx] = o;
    }
}

// ---------------- CSR fill (cursor allocation; bucket order irrelevant) ----------------
__global__ __launch_bounds__(256) void csr_fill_kernel(
    const int* __restrict__ src, const int* __restrict__ dst,
    int* __restrict__ cur, int* __restrict__ csr_src)
{
    const int tid = blockIdx.x * 256 + threadIdx.x;
    if (tid >= RR * EE) return;
    const int r = tid / EE;
    const int d = dst[tid];
    const int p = atomicAdd(&cur[r * NN + d], 1);
    csr_src[(size_t)r * EE + p] = src[tid];
}

// ---------------- pull aggregation + fused dst-normalize + residual blend ----------------
// 32 lanes per dst node; acc in registers; single 512B row write. No atomics.
__global__ __launch_bounds__(256) void pull_kernel(
    const float* __restrict__ h, const float* __restrict__ x,
    const int* __restrict__ csr, const int* __restrict__ off,
    const int* __restrict__ cnt_in, const float* __restrict__ dego_r,
    const float* __restrict__ degi_r, float* __restrict__ agg)
{
    const int tid = blockIdx.x * 256 + threadIdx.x;
    const int node = tid >> 5;
    if (node >= NN) return;
    const int lane = tid & 31;
    const int j0 = off[node];
    const int j1 = j0 + cnt_in[node];
    float4 acc = make_float4(0.f, 0.f, 0.f, 0.f);
    int j = j0;
    for (; j + 2 <= j1; j += 2) {
        const int s0 = csr[j], s1 = csr[j + 1];
        const float n0 = dego_r[s0], n1 = dego_r[s1];
        const float4 v0 = ((const float4*)(h + (size_t)s0 * DD))[lane];
        const float4 v1 = ((const float4*)(h + (size_t)s1 * DD))[lane];
        acc.x += v0.x * n0 + v1.x * n1;
        acc.y += v0.y * n0 + v1.y * n1;
        acc.z += v0.z * n0 + v1.z * n1;
        acc.w += v0.w * n0 + v1.w * n1;
    }
    if (j < j1) {
        const int s0 = csr[j];
        const float n0 = dego_r[s0];
        const float4 v0 = ((const float4*)(h + (size_t)s0 * DD))[lane];
        acc.x += v0.x * n0;
        acc.y += v0.y * n0;
        acc.z += v0.z * n0;
        acc.w += v0.w * n0;
    }
    const float nd = degi_r[node] * (1.0f - ALPHA_);
    const float4 f = ((const float4*)(x + (size_t)node * DD))[lane];
    float4 o;
    o.x = acc.x * nd + ALPHA_ * f.x;
    o.y = acc.y * nd + ALPHA_ * f.y;
    o.z = acc.z * nd + ALPHA_ * f.z;
    o.w = acc.w * nd + ALPHA_ * f.w;
    ((float4*)(agg + (size_t)node * DD))[lane] = o;
}

// ---------------- GEMM [N,128]@[128,128] + identity-map epilogue + mean-accum ----------------
__global__ __launch_bounds__(256) void gemm_ep_kernel(
    const float* __restrict__ rst, const float* __restrict__ W,
    const float* __restrict__ b, float* __restrict__ hout,
    float beta, int act)
{
    __shared__ float Wl[DD * DD];       // 64 KB
    __shared__ float rowbuf[16][DD];    // 8 KB
    __shared__ float bl[DD];
    const int tid = threadIdx.x;
    for (int i = tid; i < DD * DD / 4; i += 256)
        ((float4*)Wl)[i] = ((const float4*)W)[i];
    if (tid < DD) bl[tid] = b[tid];
    const int lane = tid & 31;
    const int ty = tid >> 5;            // 0..7
    const int r0 = ty * 2, r1 = r0 + 1;
    const float omb = 1.0f - beta;
    const int blockRow = blockIdx.x * 64;

    for (int it = 0; it < 4; ++it) {
        const int rb = blockRow + it * 16;
        __syncthreads();
        for (int i = tid; i < 16 * DD / 4; i += 256) {
            const int rr = i >> 5, cc = i & 31;
            const int grow = rb + rr;
            float4 v = make_float4(0.f, 0.f, 0.f, 0.f);
            if (grow < NN) v = ((const float4*)(rst + (size_t)grow * DD))[cc];
            ((float4*)rowbuf)[i] = v;
        }
        __syncthreads();

        float4 a0 = make_float4(0.f, 0.f, 0.f, 0.f);
        float4 a1 = make_float4(0.f, 0.f, 0.f, 0.f);
        for (int k = 0; k < DD; ++k) {
            const float4 w = ((const float4*)(Wl + k * DD))[lane];
            const float x0 = rowbuf[r0][k];
            const float x1 = rowbuf[r1][k];
            a0.x = fmaf(x0, w.x, a0.x); a0.y = fmaf(x0, w.y, a0.y);
            a0.z = fmaf(x0, w.z, a0.z); a0.w = fmaf(x0, w.w, a0.w);
            a1.x = fmaf(x1, w.x, a1.x); a1.y = fmaf(x1, w.y, a1.y);
            a1.z = fmaf(x1, w.z, a1.z); a1.w = fmaf(x1, w.w, a1.w);
        }

        const float4 bb = ((const float4*)bl)[lane];
        #pragma unroll
        for (int p = 0; p < 2; ++p) {
            const int rr = (p == 0) ? r0 : r1;
            const float4 ac = (p == 0) ? a0 : a1;
            const int grow = rb + rr;
            if (grow < NN) {
                const float4 rv = ((const float4*)rowbuf[rr])[lane];
                float4 v;
                v.x = omb * rv.x + beta * ac.x + bb.x;
                v.y = omb * rv.y + beta * ac.y + bb.y;
                v.z = omb * rv.z + beta * ac.z + bb.z;
                v.w = omb * rv.w + beta * ac.w + bb.w;
                if (act) {
                    v.x = v.x >= 0.f ? v.x : SLOPE_ * v.x;
                    v.y = v.y >= 0.f ? v.y : SLOPE_ * v.y;
                    v.z = v.z >= 0.f ? v.z : SLOPE_ * v.z;
                    v.w = v.w >= 0.f ? v.w : SLOPE_ * v.w;
                }
                float4* ho = (float4*)(hout + (size_t)grow * DD) + lane;
                float4 o = *ho;
                o.x += v.x * (1.0f / 3.0f);
                o.y += v.y * (1.0f / 3.0f);
                o.z += v.z * (1.0f / 3.0f);
                o.w += v.w * (1.0f / 3.0f);
                *ho = o;
            }
        }
    }
}

// ---------------- final linear [N,128]@[128,64] + bias ----------------
__global__ __launch_bounds__(256) void lin_kernel(
    const float* __restrict__ h, const float* __restrict__ Wlin,
    const float* __restrict__ blin, float* __restrict__ out)
{
    __shared__ float Wl[DD * OUTD];     // 32 KB
    __shared__ float rowbuf[16][DD];    // 8 KB
    __shared__ float bl[OUTD];
    const int tid = threadIdx.x;
    for (int i = tid; i < DD * OUTD / 4; i += 256)
        ((float4*)Wl)[i] = ((const float4*)Wlin)[i];
    if (tid < OUTD) bl[tid] = blin[tid];
    const int lane = tid & 15;          // 16 lanes x 4 cols = 64 cols
    const int ty = tid >> 4;            // 0..15 rows
    const int blockRow = blockIdx.x * 64;

    for (int it = 0; it < 4; ++it) {
        const int rb = blockRow + it * 16;
        __syncthreads();
        for (int i = tid; i < 16 * DD / 4; i += 256) {
            const int rr = i >> 5, cc = i & 31;
            const int grow = rb + rr;
            float4 v = make_float4(0.f, 0.f, 0.f, 0.f);
            if (grow < NN) v = ((const float4*)(h + (size_t)grow * DD))[cc];
            ((float4*)rowbuf)[i] = v;
        }
        __syncthreads();

        float4 acc = make_float4(0.f, 0.f, 0.f, 0.f);
        for (int k = 0; k < DD; ++k) {
            const float4 w = ((const float4*)(Wl + k * OUTD))[lane];
            const float xv = rowbuf[ty][k];
            acc.x = fmaf(xv, w.x, acc.x);
            acc.y = fmaf(xv, w.y, acc.y);
            acc.z = fmaf(xv, w.z, acc.z);
            acc.w = fmaf(xv, w.w, acc.w);
        }
        const int grow = rb + ty;
        if (grow < NN) {
            const float4 bb = ((const float4*)bl)[lane];
            float4 v;
            v.x = acc.x + bb.x;
            v.y = acc.y + bb.y;
            v.z = acc.z + bb.z;
            v.w = acc.w + bb.w;
            ((float4*)(out + (size_t)grow * OUTD))[lane] = v;
        }
    }
}

extern "C" void kernel_launch(void* const* d_in, const int* in_sizes, int n_in,
                              void* d_out, int out_size, void* d_ws, size_t ws_size,
                              hipStream_t stream)
{
    const float* x    = (const float*)d_in[0];
    const int*   src  = (const int*)  d_in[1];
    const int*   dst  = (const int*)  d_in[2];
    const float* W1   = (const float*)d_in[3];
    const float* b1   = (const float*)d_in[4];
    const float* W2   = (const float*)d_in[5];
    const float* b2   = (const float*)d_in[6];
    const float* Wlin = (const float*)d_in[7];
    const float* blin = (const float*)d_in[8];
    float* out = (float*)d_out;

    // workspace layout (4B units):
    // cnt_out[3N] | cnt_in[3N] | dego_r[3N] | degi_r[3N] | off[3N] | cur[3N] |
    // bsum[3*NB] | bexcl[3*NB] | csr[3E] | agg[N*D] | h1[N*D] | h2[N*D]   ~= 91 MB
    int*   cnt_out = (int*)d_ws;
    int*   cnt_in  = cnt_out + RR * NN;
    float* dego_r  = (float*)(cnt_in + RR * NN);
    float* degi_r  = dego_r + RR * NN;
    int*   off     = (int*)(degi_r + RR * NN);
    int*   cur     = off + RR * NN;
    int*   bsum    = cur + RR * NN;
    int*   bexcl   = bsum + RR * NB;
    int*   csr     = bexcl + RR * NB;
    float* agg     = (float*)(csr + (size_t)RR * EE);
    float* h1      = agg + (size_t)NN * DD;
    float* h2      = h1  + (size_t)NN * DD;

    hipMemsetAsync(cnt_out, 0, (size_t)2 * RR * NN * sizeof(int), stream);
    hipMemsetAsync(h1,      0, (size_t)NN * DD * sizeof(float), stream);
    hipMemsetAsync(h2,      0, (size_t)NN * DD * sizeof(float), stream);

    const int edge_blocks = (RR * EE + 255) / 256;
    const int node_blocks = (RR * NN + 255) / 256;
    const int pull_blocks = (NN * 32 + 255) / 256;
    const int gemm_blocks = (NN + 63) / 64;

    // ---- CSR build (once; same graph for both layers) ----
    deg_count_kernel<<<edge_blocks, 256, 0, stream>>>(src, dst, cnt_out, cnt_in);
    deg_fin_kernel<<<node_blocks, 256, 0, stream>>>(cnt_out, cnt_in, dego_r, degi_r);
    scanA_kernel<<<RR * NB, 256, 0, stream>>>(cnt_in, bsum);
    scanB_kernel<<<1, 256, 0, stream>>>(bsum, bexcl);
    scanC_kernel<<<RR * NB, 256, 0, stream>>>(cnt_in, bexcl, off, cur);
    csr_fill_kernel<<<edge_blocks, 256, 0, stream>>>(src, dst, cur, csr);

    // ---- conv1: h1 = mean_r gcn2(x, x, W1_r, b1_r, beta1, leaky) ----
    for (int r = 0; r < RR; ++r) {
        pull_kernel<<<pull_blocks, 256, 0, stream>>>(
            x, x, csr + (size_t)r * EE, off + r * NN, cnt_in + r * NN,
            dego_r + r * NN, degi_r + r * NN, agg);
        gemm_ep_kernel<<<gemm_blocks, 256, 0, stream>>>(
            agg, W1 + (size_t)r * DD * DD, b1 + r * DD, h1, BETA1_, 1);
    }
    // ---- conv2: h2 = mean_r gcn2(h1, x, W2_r, b2_r, beta2, no act) ----
    for (int r = 0; r < RR; ++r) {
        pull_kernel<<<pull_blocks, 256, 0, stream>>>(
            h1, x, csr + (size_t)r * EE, off + r * NN, cnt_in + r * NN,
            dego_r + r * NN, degi_r + r * NN, agg);
        gemm_ep_kernel<<<gemm_blocks, 256, 0, stream>>>(
            agg, W2 + (size_t)r * DD * DD, b2 + r * DD, h2, BETA2_, 0);
    }
    // ---- final linear ----
    lin_kernel<<<gemm_blocks, 256, 0, stream>>>(h2, Wlin, blin, out);
}